// Round 26
// baseline (217.673 us; speedup 1.0000x reference)
//
#include <hip/hip_runtime.h>
#include <cstdint>

typedef float  f32x4  __attribute__((ext_vector_type(4)));
typedef short  short8 __attribute__((ext_vector_type(8)));
typedef _Float16 half4 __attribute__((ext_vector_type(4)));
typedef _Float16 half8 __attribute__((ext_vector_type(8)));

// ---------- helpers ----------
__device__ __forceinline__ unsigned short f2bf(float f) {
    unsigned u = __builtin_bit_cast(unsigned, f);
    u += 0x7FFFu + ((u >> 16) & 1u);   // RNE
    return (unsigned short)(u >> 16);
}

// ---------- kernel 1: weights fp32 -> bf16 + PE table ----------
__global__ void wconv_kernel(const float* __restrict__ wq,
                             const float* __restrict__ wk,
                             const float* __restrict__ wv,
                             unsigned short* __restrict__ Wb,
                             unsigned short* __restrict__ PE) {
    if (blockIdx.x == 768) {
        for (int i = threadIdx.x; i < 512; i += 256) {   // 256 threads, 512 entries
            int l = i >> 4, e = i & 15;
            float val = 0.f;
            if (l > 0) {
                float ang = (float)l * powf(10000.f, -(float)(e >> 1) * 0.125f);
                val = (e & 1) ? cosf(ang) : sinf(ang);
            }
            PE[i] = f2bf(val);
        }
        return;
    }
    int p = blockIdx.x >> 8;                       // 0..2
    int i = ((blockIdx.x & 255) << 8) + threadIdx.x; // 0..65535
    const float* src = (p == 0) ? wq : ((p == 1) ? wk : wv);
    Wb[(p << 16) + i] = f2bf(src[i]);
}

// ---------- kernel 2: fused X0-build + QKV projection (R25, best) ----------
__global__ __launch_bounds__(256, 2) void fproj_kernel(
        const float* __restrict__ x,
        const unsigned short* __restrict__ Wb,
        const unsigned short* __restrict__ PE,
        const float* __restrict__ bq, const float* __restrict__ bk,
        const float* __restrict__ bv,
        unsigned short* __restrict__ Q, unsigned short* __restrict__ K,
        _Float16* __restrict__ V) {
    __shared__ __align__(16) char Xlds[32768];   // 64 s-rows x 512B (swz)
    __shared__ __align__(16) char Wlds[32768];   // 64 o-rows x 512B (swz)
    float* Tt = (float*)Wlds;                    // phase-1 scratch [224][32] linear

    int st = blockIdx.x;            // s-tile 0..15
    int b  = blockIdx.y;            // 0..31
    int sb = st << 6;
    int tid = threadIdx.x; int w = tid >> 6; int l = tid & 63;
    int g = l >> 4, c = l & 15;
    int wr = w >> 1, wc = w & 1;

    // ---- phase 1: build X tile [64s][256c] bf16 in swizzled LDS ----
    #pragma unroll 1
    for (int sc = 0; sc < 2; ++sc) {
        if (sc) __syncthreads();             // protect Tt reuse
        #pragma unroll
        for (int j = 0; j < 7; ++j) {
            int ch = j * 256 + tid;          // 0..1791 (16B chunks)
            int row = ch >> 3, c4 = ch & 7;
            __builtin_amdgcn_global_load_lds(
                (const unsigned int*)&x[((b * 224 + row) << 10) + sb + (sc << 5) + (c4 << 2)],
                (unsigned int*)((char*)Tt + ((j << 8) + (w << 6)) * 16), 16, 0, 0);
        }
        asm volatile("s_waitcnt vmcnt(0)\n\ts_barrier" ::: "memory");
        #pragma unroll
        for (int r = 0; r < 4; ++r) {
            int idx = r * 256 + tid;
            if (idx < 896) {
                int cc16 = idx >> 5;         // 0..27
                int sl = idx & 31;
                int s = (sc << 5) + sl;      // 0..63
                short8 v8;
                #pragma unroll
                for (int j = 0; j < 8; ++j)
                    v8[j] = (short)f2bf(Tt[(cc16 * 8 + j) * 32 + sl]);
                *(short8*)&Xlds[(s << 9) + ((cc16 ^ (s & 7)) << 4)] = v8;
            }
        }
        if (tid < 128) {
            int sl = tid >> 2;
            int cc16 = 28 + (tid & 3);
            int s = (sc << 5) + sl;
            int sg = sb + s;
            int h = sg >> 5, ww = sg & 31;
            short8 v8;
            #pragma unroll
            for (int j = 0; j < 8; ++j) {
                int ch = (cc16 - 28) * 8 + j;        // 0..31
                int i = (ch < 16) ? (ch * 32 + h) : ((ch - 16) * 32 + ww);
                v8[j] = (short)PE[i];
            }
            *(short8*)&Xlds[(s << 9) + ((cc16 ^ (s & 7)) << 4)] = v8;
        }
    }
    __syncthreads();      // Xlds complete; Tt (Wlds) free

    // ---- hoist A fragments (wave's 32 s-rows) into registers ----
    short8 af[2][8];
    #pragma unroll
    for (int i = 0; i < 2; ++i) {
        const char* ab = &Xlds[(wr * 32 + i * 16 + c) << 9];
        #pragma unroll
        for (int kk = 0; kk < 8; ++kk)
            af[i][kk] = *(const short8*)&ab[((kk * 4 + g) ^ (c & 7)) << 4];
    }

    // ---- phase 2: 12 steps (3 proj x 4 o-tiles of 64), 32KB W stage ----
    #pragma unroll 1
    for (int pj = 0; pj < 3; ++pj) {
        const float* bias = (pj == 0) ? bq : ((pj == 1) ? bk : bv);
        #pragma unroll 1
        for (int ot = 0; ot < 4; ++ot) {
            const unsigned short* Wg = Wb + (pj << 16) + (ot << 14);
            #pragma unroll
            for (int p = 0; p < 8; ++p) {
                int ch = p * 256 + tid;
                int row = ch >> 5;
                int cl = (ch & 31) ^ (row & 7);
                __builtin_amdgcn_global_load_lds(
                    (const unsigned int*)&Wg[(row << 8) + cl * 8],
                    (unsigned int*)(Wlds + ((p << 8) + (w << 6)) * 16), 16, 0, 0);
            }
            asm volatile("s_waitcnt vmcnt(0)\n\ts_barrier" ::: "memory");

            f32x4 acc[2][2];
            #pragma unroll
            for (int i = 0; i < 2; ++i)
                #pragma unroll
                for (int j = 0; j < 2; ++j) acc[i][j] = (f32x4){0.f, 0.f, 0.f, 0.f};

            const char* bb0 = &Wlds[(wc * 32 + c) << 9];
            const char* bb1 = &Wlds[(wc * 32 + 16 + c) << 9];
            __builtin_amdgcn_s_setprio(1);
            #pragma unroll
            for (int kk = 0; kk < 8; ++kk) {
                int co = ((kk * 4 + g) ^ (c & 7)) << 4;
                short8 b0 = *(const short8*)&bb0[co];
                short8 b1 = *(const short8*)&bb1[co];
                acc[0][0] = __builtin_amdgcn_mfma_f32_16x16x32_bf16(af[0][kk], b0, acc[0][0], 0, 0, 0);
                acc[0][1] = __builtin_amdgcn_mfma_f32_16x16x32_bf16(af[0][kk], b1, acc[0][1], 0, 0, 0);
                acc[1][0] = __builtin_amdgcn_mfma_f32_16x16x32_bf16(af[1][kk], b0, acc[1][0], 0, 0, 0);
                acc[1][1] = __builtin_amdgcn_mfma_f32_16x16x32_bf16(af[1][kk], b1, acc[1][1], 0, 0, 0);
            }
            __builtin_amdgcn_s_setprio(0);

            #pragma unroll
            for (int j = 0; j < 2; ++j) {
                int o = (ot << 6) + wc * 32 + j * 16 + c;
                float bbv = bias[o];
                #pragma unroll
                for (int i = 0; i < 2; ++i) {
                    int sgb = sb + wr * 32 + i * 16;
                    if (pj < 2) {
                        unsigned short* dst = (pj == 0) ? Q : K;
                        #pragma unroll
                        for (int r = 0; r < 4; ++r) {
                            float v = fmaxf(acc[i][j][r] + bbv, 0.f);
                            int s = sgb + 4 * g + r;
                            dst[(((b << 10) + s) << 8) + o] = f2bf(v);
                        }
                    } else {
                        half4 hv;
                        #pragma unroll
                        for (int r = 0; r < 4; ++r)
                            hv[r] = (_Float16)fmaxf(acc[i][j][r] + bbv, 0.f);
                        int hi = (sgb >> 4) & 1;
                        int tt = sgb >> 5;
                        *(half4*)&V[((size_t)((b << 5) + tt) << 13)
                                    + ((o << 2) + (g ^ ((o >> 1) & 3))) * 8
                                    + (hi << 2)] = hv;
                    }
                }
            }
            __syncthreads();    // all waves done reading Wlds before restage
        }
    }
}

// ---------- kernel 3: causal attention, 48KB LDS -> 3 blocks/CU ----------
// K dbuf 2x16KB; V SINGLE 16KB buffer: vread(t) into regs right after the
// drain barrier, then lgkmcnt(0)+barrier releases the V restage for t+1.
__global__ __launch_bounds__(256, 3) void attn_kernel(
        const unsigned short* __restrict__ Q,
        const unsigned short* __restrict__ K,
        const _Float16* __restrict__ V,
        float* __restrict__ out) {
    __shared__ __align__(16) char Klds[2][16384];   // 32 t-rows x 512B
    __shared__ __align__(16) char Vlds[16384];      // 1024 chunks x 16B (single)

    int bid = blockIdx.x;
    int xcd  = bid & 7;
    int qv   = (bid >> 3) & 7;
    int bhi  = (bid >> 6) & 3;
    int hf   = bid >> 8;
    int b  = (bhi << 3) | xcd;
    int qt = hf ? qv : (15 - qv);       // 0..15, 64-row q-tile

    int tid = threadIdx.x; int w = tid >> 6; int l = tid & 63;
    int g = l >> 4, c = l & 15;
    int s0 = (qt << 6) + (w << 4);      // this wave's 16 q-rows

    // ---- Q fragments ----
    short8 qf[8];
    #pragma unroll
    for (int kk = 0; kk < 8; ++kk)
        qf[kk] = *(const short8*)&Q[(((b << 10) + s0 + c) << 8) + kk * 32 + g * 8];

    float m = -1e30f, lsum = 0.f;       // lsum: per-lane partial
    f32x4 acc[16];
    #pragma unroll
    for (int i = 0; i < 16; ++i) acc[i] = (f32x4){0.f, 0.f, 0.f, 0.f};

    const unsigned short* Kb_ = &K[(size_t)b << 18];
    const _Float16*       Vb_ = &V[(size_t)b << 18];

    int nt = 2 * qt + 2;                // 32-wide t-tiles
    int dt = 2 * qt + (w >> 1);         // this wave's diagonal t-tile

    auto stageK = [&](int t, int bufi) {
        int t0 = t << 5;
        #pragma unroll
        for (int j = 0; j < 4; ++j) {
            int ch = (j << 8) + tid;            // 0..1023
            int trow = ch >> 5;
            int cl = (ch & 31) ^ (trow & 7);
            __builtin_amdgcn_global_load_lds(
                (const unsigned int*)&Kb_[((t0 + trow) << 8) + cl * 8],
                (unsigned int*)(Klds[bufi] + ((j << 8) + (w << 6)) * 16), 16, 0, 0);
        }
    };
    auto stageV = [&](int t) {
        #pragma unroll
        for (int j = 0; j < 4; ++j) {
            int ch = (j << 8) + tid;            // 0..1023
            __builtin_amdgcn_global_load_lds(
                (const unsigned int*)&Vb_[((size_t)t << 13) + ch * 8],
                (unsigned int*)(Vlds + ((j << 8) + (w << 6)) * 16), 16, 0, 0);
        }
    };

    stageK(0, 0);
    stageV(0);

    for (int t = 0; t < nt; ++t) {
        asm volatile("s_waitcnt vmcnt(0)\n\ts_barrier" ::: "memory");
        // ---- V fragments into regs (V buffer dead afterwards) ----
        half8 vread[16];
        if (t <= dt) {
            #pragma unroll
            for (int vt = 0; vt < 16; ++vt) {
                int pos = (vt << 6) + (c << 2) + (g ^ ((c >> 1) & 3));
                vread[vt] = *(const half8*)&Vlds[pos << 4];
            }
        }
        asm volatile("s_waitcnt lgkmcnt(0)\n\ts_barrier" ::: "memory");
        if (t + 1 < nt) { stageK(t + 1, (t + 1) & 1); stageV(t + 1); }
        if (t > dt) continue;                        // done; keep barrier cadence

        const char* Kl = Klds[t & 1];
        #pragma unroll
        for (int sub = 0; sub < 2; ++sub) {
            bool dmask = (t == dt) && (sub == (w & 1));
            if ((t == dt) && !(w & 1) && sub == 1) break;   // fully above diag
            int toff = sub << 4;
            // ---- QK^T from LDS (16x16x32, 2 chains) ----
            f32x4 sc0 = {0.f,0.f,0.f,0.f}, sc1 = {0.f,0.f,0.f,0.f};
            const char* kbase = &Kl[(toff + c) * 512];
            __builtin_amdgcn_s_setprio(1);
            #pragma unroll
            for (int kk = 0; kk < 8; kk += 2) {
                short8 a0 = *(const short8*)&kbase[(((kk * 4 + g)       ^ (c & 7)) << 4)];
                short8 a1 = *(const short8*)&kbase[((((kk + 1) * 4 + g) ^ (c & 7)) << 4)];
                sc0 = __builtin_amdgcn_mfma_f32_16x16x32_bf16(a0, qf[kk], sc0, 0, 0, 0);
                sc1 = __builtin_amdgcn_mfma_f32_16x16x32_bf16(a1, qf[kk + 1], sc1, 0, 0, 0);
            }
            __builtin_amdgcn_s_setprio(0);
            // ---- scale + diagonal mask ----
            float sv[4];
            #pragma unroll
            for (int r = 0; r < 4; ++r) sv[r] = (sc0[r] + sc1[r]) * 0.0625f;
            if (dmask) {
                #pragma unroll
                for (int r = 0; r < 4; ++r)
                    if (4 * g + r > c) sv[r] = -1e30f;
            }
            // ---- softmax: shuffle-free fast path ----
            float tm = fmaxf(fmaxf(sv[0], sv[1]), fmaxf(sv[2], sv[3]));
            if (!__all((int)(tm <= m + 8.f))) {          // rare slow path
                float tr = fmaxf(tm, __shfl_xor(tm, 16));
                tr = fmaxf(tr, __shfl_xor(tr, 32));
                float mnew = fmaxf(m, tr);
                float alpha = __expf(m - mnew);
                m = mnew;
                lsum *= alpha;
                #pragma unroll
                for (int i = 0; i < 16; ++i) acc[i] *= alpha;
            }
            float p[4];
            #pragma unroll
            for (int r = 0; r < 4; ++r) { p[r] = __expf(sv[r] - m); lsum += p[r]; }
            half4 pb;
            #pragma unroll
            for (int r = 0; r < 4; ++r) pb[r] = (_Float16)p[r];
            // ---- PV (16x16x16 f16) ----
            __builtin_amdgcn_s_setprio(1);
            #pragma unroll
            for (int vt = 0; vt < 16; ++vt) {
                half4 vf;
                #pragma unroll
                for (int jj = 0; jj < 4; ++jj) vf[jj] = vread[vt][sub * 4 + jj];
                acc[vt] = __builtin_amdgcn_mfma_f32_16x16x16f16(vf, pb, acc[vt], 0, 0, 0);
            }
            __builtin_amdgcn_s_setprio(0);
        }
    }

    // ---- epilogue: row-sum of lsum (only softmax shuffles), write ----
    lsum += __shfl_xor(lsum, 16);
    lsum += __shfl_xor(lsum, 32);
    float rl = 1.f / lsum;
    #pragma unroll
    for (int vt = 0; vt < 16; ++vt) {
        #pragma unroll
        for (int r = 0; r < 4; ++r)
            out[(((b << 8) + vt * 16 + 4 * g + r) << 10) + s0 + c] = acc[vt][r] * rl;
    }
}

// ---------- launcher ----------
extern "C" void kernel_launch(void* const* d_in, const int* in_sizes, int n_in,
                              void* d_out, int out_size, void* d_ws, size_t ws_size,
                              hipStream_t stream) {
    const float* x  = (const float*)d_in[0];
    const float* wq = (const float*)d_in[1];
    const float* bq = (const float*)d_in[2];
    const float* wk = (const float*)d_in[3];
    const float* bk = (const float*)d_in[4];
    const float* wv = (const float*)d_in[5];
    const float* bv = (const float*)d_in[6];
    float* out = (float*)d_out;

    char* ws = (char*)d_ws;
    unsigned short* Wb = (unsigned short*)ws;                       // 393,216 B
    unsigned short* Qb = (unsigned short*)(ws + 393216);
    unsigned short* Kb = (unsigned short*)(ws + 393216 + 16777216);
    _Float16*       Vb = (_Float16*)     (ws + 393216 + 2 * 16777216);
    unsigned short* PEt = (unsigned short*)(ws + 393216 + 3 * 16777216);

    wconv_kernel<<<769, 256, 0, stream>>>(wq, wk, wv, Wb, PEt);
    fproj_kernel<<<dim3(16, 32), 256, 0, stream>>>(x, Wb, PEt, bq, bk, bv, Qb, Kb, Vb);
    attn_kernel<<<512, 256, 0, stream>>>(Qb, Kb, Vb, out);
}

// Round 27
// 91.695 us; speedup vs baseline: 2.3739x; 2.3739x over previous
//
#include <hip/hip_runtime.h>
#include <cstdint>

typedef float  f32x4  __attribute__((ext_vector_type(4)));
typedef short  short8 __attribute__((ext_vector_type(8)));
typedef _Float16 half4 __attribute__((ext_vector_type(4)));
typedef _Float16 half8 __attribute__((ext_vector_type(8)));

// ---------- helpers ----------
__device__ __forceinline__ unsigned short f2bf(float f) {
    unsigned u = __builtin_bit_cast(unsigned, f);
    u += 0x7FFFu + ((u >> 16) & 1u);   // RNE
    return (unsigned short)(u >> 16);
}

// ---------- kernel 1: weights fp32 -> bf16 + PE table ----------
__global__ void wconv_kernel(const float* __restrict__ wq,
                             const float* __restrict__ wk,
                             const float* __restrict__ wv,
                             unsigned short* __restrict__ Wb,
                             unsigned short* __restrict__ PE) {
    if (blockIdx.x == 768) {
        for (int i = threadIdx.x; i < 512; i += 256) {   // 256 threads, 512 entries
            int l = i >> 4, e = i & 15;
            float val = 0.f;
            if (l > 0) {
                float ang = (float)l * powf(10000.f, -(float)(e >> 1) * 0.125f);
                val = (e & 1) ? cosf(ang) : sinf(ang);
            }
            PE[i] = f2bf(val);
        }
        return;
    }
    int p = blockIdx.x >> 8;                       // 0..2
    int i = ((blockIdx.x & 255) << 8) + threadIdx.x; // 0..65535
    const float* src = (p == 0) ? wq : ((p == 1) ? wk : wv);
    Wb[(p << 16) + i] = f2bf(src[i]);
}

// ---------- kernel 2: fused X0-build + QKV projection (R25, best) ----------
__global__ __launch_bounds__(256, 2) void fproj_kernel(
        const float* __restrict__ x,
        const unsigned short* __restrict__ Wb,
        const unsigned short* __restrict__ PE,
        const float* __restrict__ bq, const float* __restrict__ bk,
        const float* __restrict__ bv,
        unsigned short* __restrict__ Q, unsigned short* __restrict__ K,
        _Float16* __restrict__ V) {
    __shared__ __align__(16) char Xlds[32768];   // 64 s-rows x 512B (swz)
    __shared__ __align__(16) char Wlds[32768];   // 64 o-rows x 512B (swz)
    float* Tt = (float*)Wlds;                    // phase-1 scratch [224][32] linear

    int st = blockIdx.x;            // s-tile 0..15
    int b  = blockIdx.y;            // 0..31
    int sb = st << 6;
    int tid = threadIdx.x; int w = tid >> 6; int l = tid & 63;
    int g = l >> 4, c = l & 15;
    int wr = w >> 1, wc = w & 1;

    // ---- phase 1: build X tile [64s][256c] bf16 in swizzled LDS ----
    #pragma unroll 1
    for (int sc = 0; sc < 2; ++sc) {
        if (sc) __syncthreads();             // protect Tt reuse
        #pragma unroll
        for (int j = 0; j < 7; ++j) {
            int ch = j * 256 + tid;          // 0..1791 (16B chunks)
            int row = ch >> 3, c4 = ch & 7;
            __builtin_amdgcn_global_load_lds(
                (const unsigned int*)&x[((b * 224 + row) << 10) + sb + (sc << 5) + (c4 << 2)],
                (unsigned int*)((char*)Tt + ((j << 8) + (w << 6)) * 16), 16, 0, 0);
        }
        asm volatile("s_waitcnt vmcnt(0)\n\ts_barrier" ::: "memory");
        #pragma unroll
        for (int r = 0; r < 4; ++r) {
            int idx = r * 256 + tid;
            if (idx < 896) {
                int cc16 = idx >> 5;         // 0..27
                int sl = idx & 31;
                int s = (sc << 5) + sl;      // 0..63
                short8 v8;
                #pragma unroll
                for (int j = 0; j < 8; ++j)
                    v8[j] = (short)f2bf(Tt[(cc16 * 8 + j) * 32 + sl]);
                *(short8*)&Xlds[(s << 9) + ((cc16 ^ (s & 7)) << 4)] = v8;
            }
        }
        if (tid < 128) {
            int sl = tid >> 2;
            int cc16 = 28 + (tid & 3);
            int s = (sc << 5) + sl;
            int sg = sb + s;
            int h = sg >> 5, ww = sg & 31;
            short8 v8;
            #pragma unroll
            for (int j = 0; j < 8; ++j) {
                int ch = (cc16 - 28) * 8 + j;        // 0..31
                int i = (ch < 16) ? (ch * 32 + h) : ((ch - 16) * 32 + ww);
                v8[j] = (short)PE[i];
            }
            *(short8*)&Xlds[(s << 9) + ((cc16 ^ (s & 7)) << 4)] = v8;
        }
    }
    __syncthreads();      // Xlds complete; Tt (Wlds) free

    // ---- hoist A fragments (wave's 32 s-rows) into registers ----
    short8 af[2][8];
    #pragma unroll
    for (int i = 0; i < 2; ++i) {
        const char* ab = &Xlds[(wr * 32 + i * 16 + c) << 9];
        #pragma unroll
        for (int kk = 0; kk < 8; ++kk)
            af[i][kk] = *(const short8*)&ab[((kk * 4 + g) ^ (c & 7)) << 4];
    }

    // ---- phase 2: 12 steps (3 proj x 4 o-tiles of 64), 32KB W stage ----
    #pragma unroll 1
    for (int pj = 0; pj < 3; ++pj) {
        const float* bias = (pj == 0) ? bq : ((pj == 1) ? bk : bv);
        #pragma unroll 1
        for (int ot = 0; ot < 4; ++ot) {
            const unsigned short* Wg = Wb + (pj << 16) + (ot << 14);
            #pragma unroll
            for (int p = 0; p < 8; ++p) {
                int ch = p * 256 + tid;
                int row = ch >> 5;
                int cl = (ch & 31) ^ (row & 7);
                __builtin_amdgcn_global_load_lds(
                    (const unsigned int*)&Wg[(row << 8) + cl * 8],
                    (unsigned int*)(Wlds + ((p << 8) + (w << 6)) * 16), 16, 0, 0);
            }
            asm volatile("s_waitcnt vmcnt(0)\n\ts_barrier" ::: "memory");

            f32x4 acc[2][2];
            #pragma unroll
            for (int i = 0; i < 2; ++i)
                #pragma unroll
                for (int j = 0; j < 2; ++j) acc[i][j] = (f32x4){0.f, 0.f, 0.f, 0.f};

            const char* bb0 = &Wlds[(wc * 32 + c) << 9];
            const char* bb1 = &Wlds[(wc * 32 + 16 + c) << 9];
            __builtin_amdgcn_s_setprio(1);
            #pragma unroll
            for (int kk = 0; kk < 8; ++kk) {
                int co = ((kk * 4 + g) ^ (c & 7)) << 4;
                short8 b0 = *(const short8*)&bb0[co];
                short8 b1 = *(const short8*)&bb1[co];
                acc[0][0] = __builtin_amdgcn_mfma_f32_16x16x32_bf16(af[0][kk], b0, acc[0][0], 0, 0, 0);
                acc[0][1] = __builtin_amdgcn_mfma_f32_16x16x32_bf16(af[0][kk], b1, acc[0][1], 0, 0, 0);
                acc[1][0] = __builtin_amdgcn_mfma_f32_16x16x32_bf16(af[1][kk], b0, acc[1][0], 0, 0, 0);
                acc[1][1] = __builtin_amdgcn_mfma_f32_16x16x32_bf16(af[1][kk], b1, acc[1][1], 0, 0, 0);
            }
            __builtin_amdgcn_s_setprio(0);

            #pragma unroll
            for (int j = 0; j < 2; ++j) {
                int o = (ot << 6) + wc * 32 + j * 16 + c;
                float bbv = bias[o];
                #pragma unroll
                for (int i = 0; i < 2; ++i) {
                    int sgb = sb + wr * 32 + i * 16;
                    if (pj < 2) {
                        unsigned short* dst = (pj == 0) ? Q : K;
                        #pragma unroll
                        for (int r = 0; r < 4; ++r) {
                            float v = fmaxf(acc[i][j][r] + bbv, 0.f);
                            int s = sgb + 4 * g + r;
                            dst[(((b << 10) + s) << 8) + o] = f2bf(v);
                        }
                    } else {
                        half4 hv;
                        #pragma unroll
                        for (int r = 0; r < 4; ++r)
                            hv[r] = (_Float16)fmaxf(acc[i][j][r] + bbv, 0.f);
                        int hi = (sgb >> 4) & 1;
                        int tt = sgb >> 5;
                        *(half4*)&V[((size_t)((b << 5) + tt) << 13)
                                    + ((o << 2) + (g ^ ((o >> 1) & 3))) * 8
                                    + (hi << 2)] = hv;
                    }
                }
            }
            __syncthreads();    // all waves done reading Wlds before restage
        }
    }
}

// ---------- kernel 3: causal attention (R17/R18/R25, best: 55.7 us) ----------
__global__ __launch_bounds__(256, 2) void attn_kernel(
        const unsigned short* __restrict__ Q,
        const unsigned short* __restrict__ K,
        const _Float16* __restrict__ V,
        float* __restrict__ out) {
    __shared__ __align__(16) char Klds[2][16384];   // 32 t-rows x 512B
    __shared__ __align__(16) char Vlds[2][16384];   // 1024 chunks x 16B

    int bid = blockIdx.x;
    int xcd  = bid & 7;
    int qv   = (bid >> 3) & 7;
    int bhi  = (bid >> 6) & 3;
    int hf   = bid >> 8;
    int b  = (bhi << 3) | xcd;
    int qt = hf ? qv : (15 - qv);       // 0..15, 64-row q-tile

    int tid = threadIdx.x; int w = tid >> 6; int l = tid & 63;
    int g = l >> 4, c = l & 15;
    int s0 = (qt << 6) + (w << 4);      // this wave's 16 q-rows

    // ---- Q fragments ----
    short8 qf[8];
    #pragma unroll
    for (int kk = 0; kk < 8; ++kk)
        qf[kk] = *(const short8*)&Q[(((b << 10) + s0 + c) << 8) + kk * 32 + g * 8];

    float m = -1e30f, lsum = 0.f;       // lsum: per-lane partial
    f32x4 acc[16];
    #pragma unroll
    for (int i = 0; i < 16; ++i) acc[i] = (f32x4){0.f, 0.f, 0.f, 0.f};

    const unsigned short* Kb_ = &K[(size_t)b << 18];
    const _Float16*       Vb_ = &V[(size_t)b << 18];

    int nt = 2 * qt + 2;                // 32-wide t-tiles
    int dt = 2 * qt + (w >> 1);         // this wave's diagonal t-tile

    auto stage = [&](int t, int bufi) {
        int t0 = t << 5;
        #pragma unroll
        for (int j = 0; j < 4; ++j) {
            int ch = (j << 8) + tid;            // 0..1023
            int trow = ch >> 5;
            int cl = (ch & 31) ^ (trow & 7);
            __builtin_amdgcn_global_load_lds(
                (const unsigned int*)&Kb_[((t0 + trow) << 8) + cl * 8],
                (unsigned int*)(Klds[bufi] + ((j << 8) + (w << 6)) * 16), 16, 0, 0);
        }
        // V tile: contiguous 16KB copy (swizzle pre-baked by fproj)
        #pragma unroll
        for (int j = 0; j < 4; ++j) {
            int ch = (j << 8) + tid;            // 0..1023
            __builtin_amdgcn_global_load_lds(
                (const unsigned int*)&Vb_[((size_t)t << 13) + ch * 8],
                (unsigned int*)(Vlds[bufi] + ((j << 8) + (w << 6)) * 16), 16, 0, 0);
        }
    };

    stage(0, 0);

    for (int t = 0; t < nt; ++t) {
        asm volatile("s_waitcnt vmcnt(0)\n\ts_barrier" ::: "memory");
        if (t + 1 < nt) stage(t + 1, (t + 1) & 1);   // overlap with compute(t)
        if (t > dt) continue;                        // done; keep barrier cadence

        const char* Kl = Klds[t & 1];
        const char* Vl = Vlds[t & 1];
        // ---- V fragments: one conflict-free b128 per vt (both subs) ----
        half8 vread[16];
        #pragma unroll
        for (int vt = 0; vt < 16; ++vt) {
            int pos = (vt << 6) + (c << 2) + (g ^ ((c >> 1) & 3));
            vread[vt] = *(const half8*)&Vl[pos << 4];
        }
        #pragma unroll
        for (int sub = 0; sub < 2; ++sub) {
            bool dmask = (t == dt) && (sub == (w & 1));
            if ((t == dt) && !(w & 1) && sub == 1) break;   // fully above diag
            int toff = sub << 4;
            // ---- QK^T from LDS (16x16x32, 2 chains) ----
            f32x4 sc0 = {0.f,0.f,0.f,0.f}, sc1 = {0.f,0.f,0.f,0.f};
            const char* kbase = &Kl[(toff + c) * 512];
            __builtin_amdgcn_s_setprio(1);
            #pragma unroll
            for (int kk = 0; kk < 8; kk += 2) {
                short8 a0 = *(const short8*)&kbase[(((kk * 4 + g)       ^ (c & 7)) << 4)];
                short8 a1 = *(const short8*)&kbase[((((kk + 1) * 4 + g) ^ (c & 7)) << 4)];
                sc0 = __builtin_amdgcn_mfma_f32_16x16x32_bf16(a0, qf[kk], sc0, 0, 0, 0);
                sc1 = __builtin_amdgcn_mfma_f32_16x16x32_bf16(a1, qf[kk + 1], sc1, 0, 0, 0);
            }
            __builtin_amdgcn_s_setprio(0);
            // ---- scale + diagonal mask ----
            float sv[4];
            #pragma unroll
            for (int r = 0; r < 4; ++r) sv[r] = (sc0[r] + sc1[r]) * 0.0625f;
            if (dmask) {
                #pragma unroll
                for (int r = 0; r < 4; ++r)
                    if (4 * g + r > c) sv[r] = -1e30f;
            }
            // ---- softmax: shuffle-free fast path ----
            float tm = fmaxf(fmaxf(sv[0], sv[1]), fmaxf(sv[2], sv[3]));
            if (!__all((int)(tm <= m + 8.f))) {          // rare slow path
                float tr = fmaxf(tm, __shfl_xor(tm, 16));
                tr = fmaxf(tr, __shfl_xor(tr, 32));
                float mnew = fmaxf(m, tr);
                float alpha = __expf(m - mnew);
                m = mnew;
                lsum *= alpha;
                #pragma unroll
                for (int i = 0; i < 16; ++i) acc[i] *= alpha;
            }
            float p[4];
            #pragma unroll
            for (int r = 0; r < 4; ++r) { p[r] = __expf(sv[r] - m); lsum += p[r]; }
            half4 pb;
            #pragma unroll
            for (int r = 0; r < 4; ++r) pb[r] = (_Float16)p[r];
            // ---- PV (16x16x16 f16) ----
            __builtin_amdgcn_s_setprio(1);
            #pragma unroll
            for (int vt = 0; vt < 16; ++vt) {
                half4 vf;
                #pragma unroll
                for (int jj = 0; jj < 4; ++jj) vf[jj] = vread[vt][sub * 4 + jj];
                acc[vt] = __builtin_amdgcn_mfma_f32_16x16x16f16(vf, pb, acc[vt], 0, 0, 0);
            }
            __builtin_amdgcn_s_setprio(0);
        }
    }

    // ---- epilogue: row-sum of lsum (only softmax shuffles), write ----
    lsum += __shfl_xor(lsum, 16);
    lsum += __shfl_xor(lsum, 32);
    float rl = 1.f / lsum;
    #pragma unroll
    for (int vt = 0; vt < 16; ++vt) {
        #pragma unroll
        for (int r = 0; r < 4; ++r)
            out[(((b << 8) + vt * 16 + 4 * g + r) << 10) + s0 + c] = acc[vt][r] * rl;
    }
}

// ---------- launcher ----------
extern "C" void kernel_launch(void* const* d_in, const int* in_sizes, int n_in,
                              void* d_out, int out_size, void* d_ws, size_t ws_size,
                              hipStream_t stream) {
    const float* x  = (const float*)d_in[0];
    const float* wq = (const float*)d_in[1];
    const float* bq = (const float*)d_in[2];
    const float* wk = (const float*)d_in[3];
    const float* bk = (const float*)d_in[4];
    const float* wv = (const float*)d_in[5];
    const float* bv = (const float*)d_in[6];
    float* out = (float*)d_out;

    char* ws = (char*)d_ws;
    unsigned short* Wb = (unsigned short*)ws;                       // 393,216 B
    unsigned short* Qb = (unsigned short*)(ws + 393216);
    unsigned short* Kb = (unsigned short*)(ws + 393216 + 16777216);
    _Float16*       Vb = (_Float16*)     (ws + 393216 + 2 * 16777216);
    unsigned short* PEt = (unsigned short*)(ws + 393216 + 3 * 16777216);

    wconv_kernel<<<769, 256, 0, stream>>>(wq, wk, wv, Wb, PEt);
    fproj_kernel<<<dim3(16, 32), 256, 0, stream>>>(x, Wb, PEt, bq, bk, bv, Qb, Kb, Vb);
    attn_kernel<<<512, 256, 0, stream>>>(Qb, Kb, Vb, out);
}